// Round 1
// baseline (404.638 us; speedup 1.0000x reference)
//
#include <hip/hip_runtime.h>

// ParametricInhibition: out[b,i,h,w] = sum_j inv(I - tpl)[i,j] * act[b,j,h,w]
// tpl is circulant (size 256) -> inv(I - tpl) is circulant with first column m,
// m = IDFT( 1 / (1 - DFT(c)) ), c = first column of tpl (real symmetric -> all real,
// cosine transforms only). The einsum is then a 256x256 (M) x 256x200704 GEMM,
// done as split-bf16 MFMA (AhiBhi + AhiBlo + AloBhi) -> ~1e-3 abs error, HBM-bound.

#define IN_CH 256
#define HW    3136          // 56*56
#define TP    64            // pixels per block
#define KC    128           // K chunk staged in LDS

typedef __bf16 bf16x8 __attribute__((ext_vector_type(8)));
typedef float  f32x4  __attribute__((ext_vector_type(4)));

// d_ws layout:
//   [0,1024)                : m[256] fp32
//   [1024, 1024+131072)     : A-frag hi, [s(8)][t(16)][lane(64)][j(8)] bf16
//   [1024+131072, +131072)  : A-frag lo
#define WS_AHI_OFF 1024
#define WS_ALO_OFF (1024 + 131072)

// ---------------- kernel 1: m[256] via circulant eigen-decomposition ----------------
__global__ __launch_bounds__(256) void pi_build_m(const float* __restrict__ damp,
                                                  const float* __restrict__ width,
                                                  float* __restrict__ ws_m) {
    __shared__ float cS[256], gS[256], ctab[256];
    int t = threadIdx.x;
    float w = width[0], dmp = damp[0];

    // exact-angle cos table: angle index is (k*n) mod 256, always <= 2*pi
    ctab[t] = cosf((float)t * 0.0245436926f /* 2*pi/256 */);

    // first column of tpl: center tap zeroed (SELF_CONNECT=False), tails wrap
    int x = (t < 128) ? t : t - 256;           // signed circular offset
    float cv = 0.0f;
    if (t != 0 && x >= -31 && x <= 31) {
        float fx2 = (float)(x * x);
        float w2  = w * w;
        cv = dmp * (1.0f - fx2 / w2) * expf(-fx2 / (2.0f * w2));
    }
    cS[t] = cv;
    __syncthreads();

    // eigenvalues of tpl: lambda_k = sum_n c_n cos(2*pi*k*n/256)
    float lam = 0.0f;
    for (int n = 0; n < 256; n++) lam += cS[n] * ctab[(t * n) & 255];
    gS[t] = 1.0f / (1.0f - lam);               // eigenvalues of inv(I - tpl)
    __syncthreads();

    // first column of the inverse: m_d = (1/256) sum_k g_k cos(2*pi*k*d/256)
    float md = 0.0f;
    for (int k = 0; k < 256; k++) md += gS[k] * ctab[(t * k) & 255];
    ws_m[t] = md * (1.0f / 256.0f);
}

// ------------- kernel 2: pre-swizzle M into MFMA A-fragment order (hi/lo bf16) -------------
// A-frag layout for mfma_f32_16x16x32_bf16: lane l holds A[m = l&15][k = (l>>4)*8 + j]
__global__ __launch_bounds__(256) void pi_build_afrag(const float* __restrict__ ws_m,
                                                      bf16x8* __restrict__ ahi,
                                                      bf16x8* __restrict__ alo) {
    int gid = blockIdx.x * 256 + threadIdx.x;  // [0, 8192) = s(8) * t(16) * lane(64)
    int l = gid & 63;
    int t = (gid >> 6) & 15;
    int s = gid >> 10;
    int i = 16 * t + (l & 15);
    int kbase = 32 * s + 8 * (l >> 4);
    bf16x8 h, lo;
#pragma unroll
    for (int j = 0; j < 8; j++) {
        float v = ws_m[(i - (kbase + j)) & 255];   // M[i][k] = m[(i-k) mod 256]
        __bf16 hb = (__bf16)v;
        h[j]  = hb;
        lo[j] = (__bf16)(v - (float)hb);
    }
    ahi[gid] = h;
    alo[gid] = lo;
}

// ---------------- kernel 3: the GEMM ----------------
// block: 4 waves, 64 pixels x all 256 output channels. Wave w owns i in [64w, 64w+64).
// LDS: act tile transposed to [p][j] bf16 hi/lo, XOR-swizzled 16B columns.
__device__ __forceinline__ int lds_didx(int p, int jb) {
    int cb = (jb ^ (p & 15) ^ ((p >> 2) & 3) ^ ((p >> 4) & 3)) & 15;
    return p * 64 + cb * 4;   // dword index; 16B-aligned column
}

__global__ __launch_bounds__(256, 3) void pi_gemm(const float* __restrict__ act,
                                                  float* __restrict__ out,
                                                  const bf16x8* __restrict__ ahi,
                                                  const bf16x8* __restrict__ alo) {
    __shared__ __align__(16) unsigned int ldsHi[TP * KC / 2];  // 16 KB
    __shared__ __align__(16) unsigned int ldsLo[TP * KC / 2];  // 16 KB

    int tid  = threadIdx.x;
    int lane = tid & 63;
    int wv   = tid >> 6;

    int b    = blockIdx.x / 49;
    int tile = blockIdx.x - b * 49;
    int p0   = tile * TP;

    const float* actb = act + (size_t)b * (IN_CH * HW) + p0;
    float*       outb = out + (size_t)b * (IN_CH * HW) + p0;

    f32x4 acc[4][4] = {};

    int px4 = tid & 15;       // staging: p-group
    int jb  = tid >> 4;       // staging: 8-wide j column block within chunk
    int pl  = px4 * 4;

    for (int c = 0; c < 2; c++) {
        // ---- stage chunk: fp32 global -> split bf16 LDS, transposed [p][j] ----
        {
            const float* src = actb + (size_t)(c * KC + jb * 8) * HW + pl;
            f32x4 v[8];
#pragma unroll
            for (int jj = 0; jj < 8; jj++)
                v[jj] = *(const f32x4*)(src + (size_t)jj * HW);
#pragma unroll
            for (int pp = 0; pp < 4; pp++) {
                int p = pl + pp;
                int didx = lds_didx(p, jb);
                bf16x8 hv, lv;
#pragma unroll
                for (int jj = 0; jj < 8; jj++) {
                    float xv = v[jj][pp];
                    __bf16 hb = (__bf16)xv;
                    hv[jj] = hb;
                    lv[jj] = (__bf16)(xv - (float)hb);
                }
                *(bf16x8*)(ldsHi + didx) = hv;   // one ds_write_b128 each
                *(bf16x8*)(ldsLo + didx) = lv;
            }
        }
        __syncthreads();

        // ---- compute: 4 k-steps of 32 per chunk ----
#pragma unroll
        for (int s = 0; s < 4; s++) {
            bf16x8 bh[4], bl[4];
#pragma unroll
            for (int ni = 0; ni < 4; ni++) {
                int p   = 16 * ni + (lane & 15);
                int jbb = 4 * s + (lane >> 4);
                int didx = lds_didx(p, jbb);
                bh[ni] = *(const bf16x8*)(ldsHi + didx);  // ds_read_b128
                bl[ni] = *(const bf16x8*)(ldsLo + didx);
            }
            int sg = 4 * c + s;
#pragma unroll
            for (int ti = 0; ti < 4; ti++) {
                int t = 4 * wv + ti;
                int aidx = (sg * 16 + t) * 64 + lane;
                bf16x8 ah = ahi[aidx];    // coalesced 16B/lane, L2-resident
                bf16x8 al = alo[aidx];
#pragma unroll
                for (int ni = 0; ni < 4; ni++) {
                    acc[ti][ni] = __builtin_amdgcn_mfma_f32_16x16x32_bf16(ah, bh[ni], acc[ti][ni], 0, 0, 0);
                    acc[ti][ni] = __builtin_amdgcn_mfma_f32_16x16x32_bf16(ah, bl[ni], acc[ti][ni], 0, 0, 0);
                    acc[ti][ni] = __builtin_amdgcn_mfma_f32_16x16x32_bf16(al, bh[ni], acc[ti][ni], 0, 0, 0);
                }
            }
        }
        __syncthreads();
    }

    // ---- epilogue: C/D layout col = lane&15, row = (lane>>4)*4 + r (verified m89/m91) ----
    int col  = lane & 15;
    int rowq = (lane >> 4) * 4;
#pragma unroll
    for (int ti = 0; ti < 4; ti++) {
        int ibase = 64 * wv + 16 * ti + rowq;
#pragma unroll
        for (int ni = 0; ni < 4; ni++) {
            int p = 16 * ni + col;
#pragma unroll
            for (int r = 0; r < 4; r++) {
                outb[(size_t)(ibase + r) * HW + p] = acc[ti][ni][r];
            }
        }
    }
}

extern "C" void kernel_launch(void* const* d_in, const int* in_sizes, int n_in,
                              void* d_out, int out_size, void* d_ws, size_t ws_size,
                              hipStream_t stream) {
    const float* act   = (const float*)d_in[0];
    const float* damp  = (const float*)d_in[1];
    const float* width = (const float*)d_in[2];
    float* out = (float*)d_out;

    float*  ws_m = (float*)d_ws;
    bf16x8* ahi  = (bf16x8*)((char*)d_ws + WS_AHI_OFF);
    bf16x8* alo  = (bf16x8*)((char*)d_ws + WS_ALO_OFF);

    int batches = in_sizes[0] / (IN_CH * HW);   // 64

    pi_build_m<<<1, 256, 0, stream>>>(damp, width, ws_m);
    pi_build_afrag<<<32, 256, 0, stream>>>(ws_m, ahi, alo);
    pi_gemm<<<batches * 49, 256, 0, stream>>>(act, out, ahi, alo);
}

// Round 2
// 370.600 us; speedup vs baseline: 1.0918x; 1.0918x over previous
//
#include <hip/hip_runtime.h>

// ParametricInhibition: out[b,i,h,w] = sum_j inv(I - tpl)[i,j] * act[b,j,h,w]
// tpl circulant(256) -> M = inv(I-tpl) circulant; m = IDFT(1/(1-DFT(c))) via
// 256-pt cosine transforms (exact integer angle reduction). Einsum = GEMM
// M(256x256) x act(256x200704), done in SINGLE-term fp16 MFMA (2^-11 rel
// input rounding -> ~0.01 absmax, threshold 0.124). HBM-bound: 411 MB -> 65us floor.

#define IN_CH 256
#define HW    3136          // 56*56
#define TP    64            // pixels per block
#define KC    128           // K chunk staged in LDS

typedef _Float16 f16x8 __attribute__((ext_vector_type(8)));
typedef float    f32x4 __attribute__((ext_vector_type(4)));

// d_ws: [0, 131072) : A-frags fp16, [s(8)][t(16)][lane(64)][j(8)]

// ---------------- kernel 1: m[256] + MFMA A-fragment swizzle, one block ----------------
__global__ __launch_bounds__(256) void pi_build(const float* __restrict__ damp,
                                                const float* __restrict__ width,
                                                f16x8* __restrict__ afrag) {
    __shared__ float cS[256], gS[256], ctab[256], mS[256];
    int t = threadIdx.x;
    float w = width[0], dmp = damp[0];

    // exact-angle cos table: index is (k*n) & 255
    ctab[t] = cosf((float)t * 0.0245436926f /* 2*pi/256 */);

    // first column of tpl (center tap zeroed, tails wrap)
    int x = (t < 128) ? t : t - 256;
    float cv = 0.0f;
    if (t != 0 && x >= -31 && x <= 31) {
        float fx2 = (float)(x * x);
        float w2  = w * w;
        cv = dmp * (1.0f - fx2 / w2) * expf(-fx2 / (2.0f * w2));
    }
    cS[t] = cv;
    __syncthreads();

    float lam = 0.0f;
#pragma unroll 8
    for (int n = 0; n < 256; n++) lam += cS[n] * ctab[(t * n) & 255];
    gS[t] = 1.0f / (1.0f - lam);
    __syncthreads();

    float md = 0.0f;
#pragma unroll 8
    for (int k = 0; k < 256; k++) md += gS[k] * ctab[(t * k) & 255];
    mS[t] = md * (1.0f / 256.0f);
    __syncthreads();

    // A-frag layout (mfma_f32_16x16x32): lane l holds A[m = l&15][k = (l>>4)*8 + j]
#pragma unroll
    for (int g = 0; g < 32; g++) {
        int gid = g * 256 + t;                 // [0, 8192)
        int l  = gid & 63;
        int tt = (gid >> 6) & 15;
        int s  = gid >> 10;
        int i     = 16 * tt + (l & 15);
        int kbase = 32 * s + 8 * (l >> 4);
        f16x8 h;
#pragma unroll
        for (int j = 0; j < 8; j++)
            h[j] = (_Float16)mS[(i - (kbase + j)) & 255];   // M[i][k] = m[(i-k) & 255]
        afrag[gid] = h;
    }
}

// ---------------- kernel 2: the GEMM ----------------
// block: 4 waves; 64 pixels x 256 output channels; wave w owns i in [64w, 64w+64).
// LDS: act chunk transposed to [p][k'] fp16, XOR-swizzled 16B columns (16 KB).
__device__ __forceinline__ int lds_didx(int p, int cb16) {
    int cb = (cb16 ^ (p & 15) ^ ((p >> 2) & 3) ^ ((p >> 4) & 3)) & 15;
    return p * 64 + cb * 4;   // dword index; 256B per p-row, 16 cols of 16B
}

__global__ __launch_bounds__(256, 4) void pi_gemm(const float* __restrict__ act,
                                                  float* __restrict__ out,
                                                  const f16x8* __restrict__ afrag) {
    __shared__ __align__(16) unsigned int lds[TP * KC / 2];   // 16 KB

    int tid  = threadIdx.x;
    int lane = tid & 63;
    int wv   = tid >> 6;

    int b    = blockIdx.x / 49;
    int tile = blockIdx.x - b * 49;
    int p0   = tile * TP;

    const float* actb = act + (size_t)b * (IN_CH * HW) + p0;
    float*       outb = out + (size_t)b * (IN_CH * HW) + p0;

    f32x4 acc[4][4] = {};

    int pl = 4 * (tid & 15);   // staging: 4 consecutive pixels
    int jb = tid >> 4;         // staging: 8-wide channel block within chunk (0..15)

    for (int c = 0; c < 2; c++) {
        // ---- stage: fp32 global -> fp16 LDS, transposed [p][k'] ----
        {
            const float* src = actb + (size_t)(c * KC + jb * 8) * HW + pl;
            f32x4 v[8];
#pragma unroll
            for (int jj = 0; jj < 8; jj++)
                v[jj] = *(const f32x4*)(src + (size_t)jj * HW);
#pragma unroll
            for (int pp = 0; pp < 4; pp++) {
                int p = pl + pp;
                int didx = lds_didx(p, jb);
                f16x8 hv;
#pragma unroll
                for (int jj = 0; jj < 8; jj++)
                    hv[jj] = (_Float16)v[jj][pp];
                *(f16x8*)(lds + didx) = hv;      // one ds_write_b128
            }
        }
        __syncthreads();

        // ---- compute: 4 k-steps of 32 ----
#pragma unroll
        for (int s = 0; s < 4; s++) {
            f16x8 bh[4];
#pragma unroll
            for (int ni = 0; ni < 4; ni++) {
                int p    = 16 * ni + (lane & 15);
                int cb16 = 4 * s + (lane >> 4);
                bh[ni] = *(const f16x8*)(lds + lds_didx(p, cb16));   // ds_read_b128
            }
            int sg = 4 * c + s;
#pragma unroll
            for (int ti = 0; ti < 4; ti++) {
                int t = 4 * wv + ti;
                f16x8 ah = afrag[(sg * 16 + t) * 64 + lane];  // 16B/lane, L2-hot (128 KB)
#pragma unroll
                for (int ni = 0; ni < 4; ni++)
                    acc[ti][ni] = __builtin_amdgcn_mfma_f32_16x16x32_f16(ah, bh[ni], acc[ti][ni], 0, 0, 0);
            }
        }
        __syncthreads();
    }

    // ---- epilogue: C/D layout col = lane&15, row = (lane>>4)*4 + r ----
    int col  = lane & 15;
    int rowq = (lane >> 4) * 4;
#pragma unroll
    for (int ti = 0; ti < 4; ti++) {
        int ibase = 64 * wv + 16 * ti + rowq;
#pragma unroll
        for (int ni = 0; ni < 4; ni++) {
            int p = 16 * ni + col;
#pragma unroll
            for (int r = 0; r < 4; r++)
                outb[(size_t)(ibase + r) * HW + p] = acc[ti][ni][r];
        }
    }
}

extern "C" void kernel_launch(void* const* d_in, const int* in_sizes, int n_in,
                              void* d_out, int out_size, void* d_ws, size_t ws_size,
                              hipStream_t stream) {
    const float* act   = (const float*)d_in[0];
    const float* damp  = (const float*)d_in[1];
    const float* width = (const float*)d_in[2];
    float* out = (float*)d_out;

    f16x8* afrag = (f16x8*)d_ws;
    int batches = in_sizes[0] / (IN_CH * HW);   // 64

    pi_build<<<1, 256, 0, stream>>>(damp, width, afrag);
    pi_gemm<<<batches * 49, 256, 0, stream>>>(act, out, afrag);
}